// Round 7
// baseline (352.843 us; speedup 1.0000x reference)
//
#include <hip/hip_runtime.h>
#include <math.h>

#define L_NUM 4
#define K_CB  2048
#define D_DIM 256
#define N_ROWS 32768
#define ROWS_B 64         // rows per block
#define CAP 56            // per-row candidate slots (LDS)
#define WACC  0.12f       // collect window (>= 2x worst-case fp16 dot err ~0.032)
#define WACC2 0.125f      // filter window (collect + packing quantization margin)

typedef _Float16 half8 __attribute__((ext_vector_type(8)));
typedef _Float16 half4v __attribute__((ext_vector_type(4)));
typedef float f32x16 __attribute__((ext_vector_type(16)));

__device__ __forceinline__ void gl_lds16(const void* g, void* l) {
  __builtin_amdgcn_global_load_lds(
      (const __attribute__((address_space(1))) void*)g,
      (__attribute__((address_space(3))) void*)l, 16, 0, 0);
}
// monotone float<->uint encoding for atomicMax on floats
__device__ __forceinline__ unsigned fenc(float f) {
  unsigned u = __float_as_uint(f);
  return (u & 0x80000000u) ? ~u : (u | 0x80000000u);
}
__device__ __forceinline__ float fdec(unsigned k) {
  unsigned u = (k & 0x80000000u) ? (k ^ 0x80000000u) : ~k;
  return __uint_as_float(u);
}

// ---------- prep: cbn fp32 (row-major) + cb16 image, chunked for 256x32h tiles ----------
// chunk g (64/layer) = cols [(g>>3)*256, +256), K-halves [(g&7)*32, +32)
// within chunk: [4 subslots][256 cols][8 halves] = 16 KB
__global__ __launch_bounds__(64)
void prep_all_kernel(const float* __restrict__ cb,
                     float* __restrict__ cbn,
                     _Float16* __restrict__ cb16) {
  const int b = blockIdx.x;            // l*2048 + k
  const int k = b & 2047, l = b >> 11;
  const int lane = threadIdx.x;        // 4 dims each
  float4 v = reinterpret_cast<const float4*>(cb + (size_t)b * D_DIM)[lane];
  float s = v.x*v.x + v.y*v.y + v.z*v.z + v.w*v.w;
  #pragma unroll
  for (int m = 1; m < 64; m <<= 1) s += __shfl_xor(s, m, 64);
  const float den = fmaxf(sqrtf(s), 1e-12f);
  v.x /= den; v.y /= den; v.z /= den; v.w /= den;   // true division = reference rounding
  reinterpret_cast<float4*>(cbn + (size_t)b * D_DIM)[lane] = v;
  half4v h;
  h[0] = (_Float16)v.x; h[1] = (_Float16)v.y; h[2] = (_Float16)v.z; h[3] = (_Float16)v.w;
  const int ct = k >> 8, col = k & 255;
  const int kc    = lane >> 3;             // dim/32  -> chunk K index
  const int sslot = (lane >> 1) & 3;       // (dim&31)/8
  const int rem   = (lane & 1) * 4;        // dim&7
  const size_t off = (size_t)l * (K_CB * D_DIM)
                   + (size_t)(ct * 8 + kc) * 8192
                   + (size_t)sslot * 2048 + (size_t)col * 8 + rem;
  *(half4v*)(cb16 + off) = h;
}

// ---------- fused: 64 rows/block, 2 blocks/CU, 4 layers, GEMM+collect+exact re-rank ----------
__global__ __launch_bounds__(256, 2)
void rq_fused_kernel(const float* __restrict__ x,
                     const float* __restrict__ cb,
                     const float* __restrict__ cbn,
                     const _Float16* __restrict__ cb16,
                     float* __restrict__ out_ids,
                     float* __restrict__ out_dec,
                     double* __restrict__ dloss) {
  extern __shared__ char sm[];
  _Float16* A16   = (_Float16*)sm;                     // [32 Ksub][64 rows][8h] 32 KB
  _Float16* Bs    = (_Float16*)(sm + 32768);           // 2 x [4 sub][256 cols][8h] 16 KB each
  unsigned* cp    = (unsigned*)(sm + 65536);           // [64][CAP] packed (q<<11|idx)
  int*      cn    = (int*)(sm + 65536 + 64*CAP*4);     // [64]
  unsigned* gmax  = (unsigned*)((char*)cn + 256);      // [64] running approx max (fenc)
  unsigned* bestp = (unsigned*)((char*)gmax + 256);    // [64] best packed (fallback)

  const int t = threadIdx.x;
  const int wid = t >> 6, ln = t & 63;
  const int l31 = ln & 31, hl = ln >> 5;
  const int rowg = wid >> 1, colg = wid & 1;           // 2 row-groups x 2 col-groups
  const int urow = t >> 2, qo = (t & 3) * 64;          // r-owner mapping: 4 thr/row
  const int row0 = blockIdx.x * ROWS_B;
  const int mrow = rowg * 32 + l31;                    // this lane's output row

  // ---- load x quarter into r regs; build A16 (layer-0 input) ----
  float r[64];
  {
    const float4* xg = (const float4*)(x + (size_t)(row0 + urow) * D_DIM + qo);
    #pragma unroll
    for (int i = 0; i < 16; ++i) {
      const float4 a = xg[i];
      r[i*4+0]=a.x; r[i*4+1]=a.y; r[i*4+2]=a.z; r[i*4+3]=a.w;
    }
  }
  #pragma unroll
  for (int j = 0; j < 8; ++j) {
    half8 h;
    #pragma unroll
    for (int e = 0; e < 8; ++e) h[e] = (_Float16)r[j*8+e];
    const int slot = (t & 3) * 8 + j;                  // global K-subslot
    *(half8*)(A16 + slot*512 + urow*8) = h;
  }
  if (t < 64) { cn[t] = 0; gmax[t] = 0u; bestp[t] = 0u; }
  int id0 = 0, id1 = 0, id2 = 0, id3 = 0;
  double lloss = 0.0;

  #pragma unroll 1
  for (int l = 0; l < L_NUM; ++l) {
    const char* Bimg = (const char*)cb16 + (size_t)l * (K_CB * D_DIM * 2);
    {
      char* dst = (char*)Bs;
      #pragma unroll
      for (int i = 0; i < 4; ++i)
        gl_lds16(Bimg + t*16 + i*4096, dst + t*16 + i*4096);
    }
    __syncthreads();   // A16 ready, resets visible, chunk0 landed

    f32x16 acc[4];     // [bi] -> cols colg*128 + bi*32 + (reg,hl); rows = lane

    #pragma unroll 1
    for (int g = 0; g < 64; ++g) {
      if ((g & 7) == 0) {
        #pragma unroll
        for (int bi = 0; bi < 4; ++bi)
          #pragma unroll
          for (int e = 0; e < 16; ++e) acc[bi][e] = 0.f;
      }
      if (g < 63) {                      // prefetch next chunk into other buffer
        char* dst = (char*)Bs + ((g + 1) & 1) * 16384;
        const char* src = Bimg + (size_t)(g + 1) * 16384;
        #pragma unroll
        for (int i = 0; i < 4; ++i)
          gl_lds16(src + t*16 + i*4096, dst + t*16 + i*4096);
      }
      const _Float16* Bb = Bs + (g & 1) * 8192;
      const int kc = g & 7;
      #pragma unroll
      for (int ks2 = 0; ks2 < 2; ++ks2) {
        const int sb = ks2*2 + hl;                     // chunk-local subslot
        const int sa = kc*4 + sb;                      // global K-subslot for A
        const half8 af = *(const half8*)(A16 + sa*512 + mrow*8);
        half8 bf[4];
        #pragma unroll
        for (int bi = 0; bi < 4; ++bi)
          bf[bi] = *(const half8*)(Bb + sb*2048 + (colg*128 + bi*32 + l31)*8);
        #pragma unroll
        for (int bi = 0; bi < 4; ++bi)
          acc[bi] = __builtin_amdgcn_mfma_f32_32x32x16_f16(bf[bi], af, acc[bi], 0, 0, 0);
      }
      if ((g & 7) == 7) {                // epilogue per 256-col tile (lane-local rows)
        const int ct = g >> 3;
        // tree max over the 64 lane-local scores
        float m4[4];
        #pragma unroll
        for (int bi = 0; bi < 4; ++bi) {
          float m0 = fmaxf(fmaxf(acc[bi][0], acc[bi][1]), fmaxf(acc[bi][2], acc[bi][3]));
          float m1 = fmaxf(fmaxf(acc[bi][4], acc[bi][5]), fmaxf(acc[bi][6], acc[bi][7]));
          float m2 = fmaxf(fmaxf(acc[bi][8], acc[bi][9]), fmaxf(acc[bi][10], acc[bi][11]));
          float m3 = fmaxf(fmaxf(acc[bi][12], acc[bi][13]), fmaxf(acc[bi][14], acc[bi][15]));
          m4[bi] = fmaxf(fmaxf(m0, m1), fmaxf(m2, m3));
        }
        const float m = fmaxf(fmaxf(m4[0], m4[1]), fmaxf(m4[2], m4[3]));
        atomicMax(&gmax[mrow], fenc(m));
        const float thr = fdec(gmax[mrow]) - WACC;     // >= own m - WACC; stale=superset-safe
        #pragma unroll
        for (int bi = 0; bi < 4; ++bi)
          #pragma unroll
          for (int rg = 0; rg < 16; ++rg) {
            const float v = acc[bi][rg];
            if (v >= thr) {
              const unsigned q = (unsigned)((v + 64.f) * 16384.f);   // monotone pack
              const unsigned cidx = (unsigned)(ct*256 + colg*128 + bi*32
                                               + 4*hl + (rg & 3) + 8*(rg >> 2));
              const unsigned pk = (q << 11) | cidx;
              atomicMax(&bestp[mrow], pk);             // unconditional fallback
              const int slot = atomicAdd(&cn[mrow], 1);
              if (slot < CAP) cp[mrow*CAP + slot] = pk;
            }
          }
      }
      __syncthreads();
    }

    // ---- tail: filter + exact double re-rank + residual/loss update ----
    {
      const float thr2 = fdec(gmax[urow]) - WACC2;
      const int m = min(cn[urow], CAP);
      double bsc = (double)INFINITY; int bidx = 0x7fffffff;
      #pragma unroll 1
      for (int j = 0; j <= m; ++j) {                   // j==m: bestp fallback, always ranked
        const unsigned p = (j < m) ? cp[urow*CAP + j] : bestp[urow];
        const float v = (float)(p >> 11) * (1.f/16384.f) - 64.f;
        if (j < m && v < thr2) continue;               // uniform within the 4-thread row group
        const int cidx = (int)(p & 2047u);
        const float4* cpn = (const float4*)(cbn + ((size_t)l*K_CB + cidx)*D_DIM + qo);
        double s = 0.0, n2 = 0.0;
        #pragma unroll
        for (int i = 0; i < 16; ++i) {
          const float4 a = cpn[i];
          s  = fma((double)r[i*4+0], (double)a.x, s);
          s  = fma((double)r[i*4+1], (double)a.y, s);
          s  = fma((double)r[i*4+2], (double)a.z, s);
          s  = fma((double)r[i*4+3], (double)a.w, s);
          n2 = fma((double)a.x, (double)a.x, n2);
          n2 = fma((double)a.y, (double)a.y, n2);
          n2 = fma((double)a.z, (double)a.z, n2);
          n2 = fma((double)a.w, (double)a.w, n2);
        }
        s  += __shfl_xor(s, 1, 64);  s  += __shfl_xor(s, 2, 64);
        n2 += __shfl_xor(n2, 1, 64); n2 += __shfl_xor(n2, 2, 64);
        const double sc = -2.0 * s + n2;
        if (sc < bsc || (sc == bsc && cidx < bidx)) { bsc = sc; bidx = cidx; }
      }
      bidx &= 2047;                                     // provably valid; belt-and-braces
      if (l == 0) id0 = bidx; else if (l == 1) id1 = bidx;
      else if (l == 2) id2 = bidx; else id3 = bidx;
      if ((t & 3) == 0) out_ids[(size_t)(row0 + urow)*L_NUM + l] = (float)bidx;

      // r -= raw q ; loss += ||r_new||^2
      const float4* qg = (const float4*)(cb + ((size_t)l*K_CB + bidx)*D_DIM + qo);
      #pragma unroll
      for (int i = 0; i < 16; ++i) {
        const float4 q = qg[i];
        r[i*4+0] -= q.x; r[i*4+1] -= q.y; r[i*4+2] -= q.z; r[i*4+3] -= q.w;
        lloss += (double)r[i*4+0]*r[i*4+0] + (double)r[i*4+1]*r[i*4+1]
               + (double)r[i*4+2]*r[i*4+2] + (double)r[i*4+3]*r[i*4+3];
      }
      if (l < 3) {                      // rebuild A16 for next layer
        #pragma unroll
        for (int j = 0; j < 8; ++j) {
          half8 h;
          #pragma unroll
          for (int e = 0; e < 8; ++e) h[e] = (_Float16)r[j*8+e];
          const int slot = (t & 3) * 8 + j;
          *(half8*)(A16 + slot*512 + urow*8) = h;
        }
      }
    }
    __syncthreads();                    // tail reads of cp/gmax/bestp + A16 writes retired
    if (l < 3 && t < 64) { cn[t] = 0; gmax[t] = 0u; bestp[t] = 0u; }
    // next layer's stage0 + barrier separates these resets from first pushes
  }

  // ---- decoded = ((q0+q1)+q2)+q3 sequential fp32 (reference rounding) ----
  {
    float dec[64];
    #pragma unroll
    for (int l2 = 0; l2 < L_NUM; ++l2) {
      const int idl = (l2 == 0) ? id0 : (l2 == 1) ? id1 : (l2 == 2) ? id2 : id3;
      const float4* qg = (const float4*)(cb + ((size_t)l2*K_CB + idl)*D_DIM + qo);
      #pragma unroll
      for (int i = 0; i < 16; ++i) {
        const float4 q = qg[i];
        if (l2 == 0) { dec[i*4+0]=q.x; dec[i*4+1]=q.y; dec[i*4+2]=q.z; dec[i*4+3]=q.w; }
        else { dec[i*4+0]+=q.x; dec[i*4+1]+=q.y; dec[i*4+2]+=q.z; dec[i*4+3]+=q.w; }
      }
    }
    float4* dg = (float4*)(out_dec + (size_t)(row0 + urow)*D_DIM + qo);
    #pragma unroll
    for (int i = 0; i < 16; ++i)
      dg[i] = make_float4(dec[i*4+0], dec[i*4+1], dec[i*4+2], dec[i*4+3]);
  }

  // ---- loss reduction (lw overlays cp; all cp reads retired before last barrier) ----
  double* lw = (double*)cp;
  #pragma unroll
  for (int m = 1; m < 64; m <<= 1) lloss += __shfl_xor(lloss, m, 64);
  if (ln == 0) lw[wid] = lloss;
  __syncthreads();
  if (t == 0) atomicAdd(dloss, lw[0] + lw[1] + lw[2] + lw[3]);
}

__global__ void rq_fin_kernel(const double* __restrict__ dls, float* __restrict__ out_loss) {
  // loss = sum_l (1 + BETA) * ||r-q||^2 / n_elem  (codebook and commitment terms equal)
  out_loss[0] = (float)(dls[0] * 1.25 / 8388608.0);
}

extern "C" void kernel_launch(void* const* d_in, const int* in_sizes, int n_in,
                              void* d_out, int out_size, void* d_ws, size_t ws_size,
                              hipStream_t stream) {
  const float* x  = (const float*)d_in[0];
  const float* cb = (const float*)d_in[1];
  float* out      = (float*)d_out;
  float* out_ids  = out;                                   // [N][4] as float
  float* out_dec  = out + (size_t)N_ROWS * L_NUM;          // [N][256]
  float* out_loss = out_dec + (size_t)N_ROWS * D_DIM;

  char* w = (char*)d_ws;
  double* dls = (double*)w;                   w += 256;
  float* cbn = (float*)w;                     w += (size_t)L_NUM*K_CB*D_DIM*4;
  _Float16* cb16 = (_Float16*)w;              w += (size_t)L_NUM*K_CB*D_DIM*2;

  hipMemsetAsync(dls, 0, sizeof(double), stream);
  prep_all_kernel<<<L_NUM*K_CB, 64, 0, stream>>>(cb, cbn, cb16);

  const size_t smem = 32768 + 32768 + 64*CAP*4 + 256 + 256 + 256;   // 80640 B
  hipFuncSetAttribute(reinterpret_cast<const void*>(rq_fused_kernel),
                      hipFuncAttributeMaxDynamicSharedMemorySize, (int)smem);
  rq_fused_kernel<<<N_ROWS/ROWS_B, 256, smem, stream>>>(x, cb, cbn, cb16,
                                                        out_ids, out_dec, dls);
  rq_fin_kernel<<<1, 1, 0, stream>>>(dls, out_loss);
}